// Round 1
// 621.748 us; speedup vs baseline: 1.3056x; 1.3056x over previous
//
#include <hip/hip_runtime.h>

// Resample2d: B=8, C=64, H=256, W=256, ks=4, dilation=1, sigma=5.
// R1 finding: TA/address-divergence bound -> collapsed 4 x-taps into one
// unaligned 16B load (global_load_dwordx4): 4 row-gathers/channel.
// R2 counters: VALUBusy 5%, all pipes idle, FETCH_SIZE 2.07 GB = 15.4x the
// 134 MB image at 3.36 TB/s -> HBM-bound on OVER-FETCH, not TA. Cause:
// round-robin blockIdx->XCD puts adjacent-h blocks (which share ~90% of
// their gathered rows) on different, non-coherent per-XCD L2s.
// R3 change: XCD-chunked swizzle. Grid 2048 = 8 XCDs x 256; dispatch i ->
// logical (i&7)*256 + (i>>3), so XCD k owns image b=k with consecutive h.
// Concurrent blocks per XCD cover a contiguous h-window; the lockstep
// 64-channel sweep keeps the per-channel working set (~150-500 KB) in the
// 4 MiB L2 -> cross-block row reuse moves from HBM into L2.

constexpr int Bc = 8, Cc = 64, Hc = 256, Wc = 256;
constexpr int HWc = Hc * Wc;

typedef float f4 __attribute__((ext_vector_type(4)));

__device__ __forceinline__ f4 load16_u(const float* p) {
  f4 r;
  __builtin_memcpy(&r, p, 16);  // align-4 16B load -> global_load_dwordx4
  return r;
}

__global__ __launch_bounds__(256) void resample2d_kernel(
    const float* __restrict__ img, const float* __restrict__ flow,
    float* __restrict__ out) {
  // XCD-chunked swizzle: 2048 blocks, 8 XCDs, hardware assigns dispatch
  // index round-robin (i & 7 == XCD id). Chunk = 256 blocks = one image.
  const int logical = ((blockIdx.x & 7) << 8) | (blockIdx.x >> 3);
  const int b = logical >> 8;          // 256 rows per image
  const int h = logical & 255;
  const int w = threadIdx.x;           // W == 256 == blockDim.x
  const int hw = (h << 8) | w;

  const float inv2s2 = 1.0f / 50.0f;   // 1/(2*sigma^2), sigma=5

  const float* flowb = flow + (size_t)b * 2 * HWc;
  const float fx = flowb[hw];
  const float fy = flowb[HWc + hw];
  const float xf = (float)w + fx;
  const float yf = (float)h + fy;
  const float x0 = floorf(xf);
  const float y0 = floorf(yf);
  const int x0i = (int)x0;

  float wx[4], wy[4];
  int yi[4], xi[4];
  float sx = 0.f, sy = 0.f;
#pragma unroll
  for (int j = 0; j < 4; ++j) {
    const float dx = x0 + (float)j - xf;
    wx[j] = __expf(-dx * dx * inv2s2);
    sx += wx[j];
    xi[j] = min(max(x0i + j, 0), Wc - 1);

    const float dy = y0 + (float)j - yf;
    wy[j] = __expf(-dy * dy * inv2s2);
    sy += wy[j];
    yi[j] = min(max((int)y0 + j, 0), Hc - 1);
  }
  const float inv_wsum = 1.0f / (sx * sy + 1e-8f);

  // Fold 1/wsum into the y-weights; row byte-offsets.
  int rowoff[4];
#pragma unroll
  for (int i = 0; i < 4; ++i) {
    wy[i] *= inv_wsum;
    rowoff[i] = yi[i] * Wc;
  }

  const bool interior = (x0i >= 0) & (x0i <= Wc - 4);

  const float* imgb = img + (size_t)b * Cc * HWc;
  float* outp = out + (size_t)b * Cc * HWc + hw;

  if (interior) {
    // Fast path: 4 unaligned 16B row loads per channel.
#pragma unroll 4
    for (int c = 0; c < Cc; ++c) {
      const float* p = imgb + (size_t)c * HWc + x0i;
      float acc = 0.f;
#pragma unroll
      for (int i = 0; i < 4; ++i) {
        const f4 v = load16_u(p + rowoff[i]);
        float r = v.x * wx[0];
        r = fmaf(v.y, wx[1], r);
        r = fmaf(v.z, wx[2], r);
        r = fmaf(v.w, wx[3], r);
        acc = fmaf(r, wy[i], acc);
      }
      outp[(size_t)c * HWc] = acc;
    }
  } else {
    // Border path: 16 scalar clamped gathers per channel.
#pragma unroll 2
    for (int c = 0; c < Cc; ++c) {
      const float* p = imgb + (size_t)c * HWc;
      float acc = 0.f;
#pragma unroll
      for (int i = 0; i < 4; ++i) {
        float r = 0.f;
#pragma unroll
        for (int j = 0; j < 4; ++j) r = fmaf(p[rowoff[i] + xi[j]], wx[j], r);
        acc = fmaf(r, wy[i], acc);
      }
      outp[(size_t)c * HWc] = acc;
    }
  }
}

extern "C" void kernel_launch(void* const* d_in, const int* in_sizes, int n_in,
                              void* d_out, int out_size, void* d_ws, size_t ws_size,
                              hipStream_t stream) {
  const float* img = (const float*)d_in[0];   // (8,64,256,256) fp32
  const float* flow = (const float*)d_in[1];  // (8,2,256,256) fp32
  float* out = (float*)d_out;                 // (8,64,256,256) fp32

  dim3 grid(Bc * Hc);   // one block per (b, h) row, XCD-swizzled in-kernel
  dim3 block(Wc);
  hipLaunchKernelGGL(resample2d_kernel, grid, block, 0, stream, img, flow, out);
}

// Round 2
// 559.631 us; speedup vs baseline: 1.4505x; 1.1110x over previous
//
#include <hip/hip_runtime.h>

// Resample2d: B=8, C=64, H=256, W=256, ks=4, dilation=1, sigma=5.
// R1: TA/address-divergence bound -> 4 unaligned dwordx4 row-gathers/channel.
// R2: FETCH 2.07 GB (15x image) -> XCD-chunked swizzle; FETCH -> 0.3 GB (match).
// R3 counters: dur only 1.44x better; HBM 12% peak, VALUBusy 7%, nothing busy.
//   -> bound by L2 REQUEST RATE: 2.1M divergent wave-gathers x ~27 sectors each.
// R4: move gathers off the TA/L2 path entirely. Per block = 4 output rows of
// one (b,h)-tile; per channel, stage a 64-row span (64 KB LDS) with coalesced
// global_load_lds_dwordx4 (1 KB contiguous per wave-instr, ~8 sectors), then
// do the 16-tap conv as LDS reads (DS pipe, bank-parallel, no TA). Span covers
// |fy| <= ~30 (3.75 sigma); rare out-of-span outputs take a global slow path,
// x-border lanes take a clamped-index LDS path. Grid 512 = 8 XCDs x 64 tiles;
// XCD k owns image k, all 64 of its blocks co-resident (2/CU, 128 KB LDS/CU)
// -> per-channel plane (256 KB) stays L2-hot across the whole XCD.

constexpr int Bc = 8, Cc = 64, Hc = 256, Wc = 256;
constexpr int HWc = Hc * Wc;
constexpr int SPAN = 64;   // staged rows per channel (64 KB LDS)
constexpr int TROWS = 4;   // output rows per block

typedef __attribute__((address_space(3))) uint32_t lds_u32;
typedef const __attribute__((address_space(1))) uint32_t glb_u32;

__global__ __launch_bounds__(256, 2) void resample2d_kernel(
    const float* __restrict__ img, const float* __restrict__ flow,
    float* __restrict__ out) {
  __shared__ float smem[SPAN * Wc];  // 65536 B

  // XCD-chunked swizzle: dispatch i -> XCD (i&7); XCD k owns image b=k.
  const int b = blockIdx.x & 7;
  const int tile = blockIdx.x >> 3;  // 0..63
  const int h0 = tile << 2;
  const int t = threadIdx.x;         // 0..255
  const int w = t;                   // W == blockDim.x
  const int wv = t >> 6;             // wave id 0..3

  const float inv2s2 = 1.0f / 50.0f;  // 1/(2*sigma^2), sigma=5
  const int y_lo = min(max(h0 - 30, 0), Hc - SPAN);  // span [y_lo, y_lo+63]
  const int ylo256 = y_lo << 8;

  const float* flowb = flow + (size_t)b * 2 * HWc;

  // Per-output-row precompute: weights, LDS row offsets, path predicates.
  float wx[TROWS][4], wyn[TROWS][4];
  int lrow[TROWS][4];  // (yi_clamped - y_lo) * 256  (valid as global via +ylo256)
  int x0[TROWS];
  bool yok[TROWS], xok[TROWS];

#pragma unroll
  for (int r = 0; r < TROWS; ++r) {
    const int hw = ((h0 + r) << 8) | w;
    const float fx = flowb[hw];
    const float fy = flowb[HWc + hw];
    const float xf = (float)w + fx;
    const float yf = (float)(h0 + r) + fy;
    const float x0f = floorf(xf);
    const float y0f = floorf(yf);
    x0[r] = (int)x0f;
    const int y0i = (int)y0f;
    float sx = 0.f, sy = 0.f;
    float wyt[4];
#pragma unroll
    for (int j = 0; j < 4; ++j) {
      const float dx = x0f + (float)j - xf;
      wx[r][j] = __expf(-dx * dx * inv2s2);
      sx += wx[r][j];
      const float dy = y0f + (float)j - yf;
      wyt[j] = __expf(-dy * dy * inv2s2);
      sy += wyt[j];
      const int yi = min(max(y0i + j, 0), Hc - 1);
      lrow[r][j] = (yi - y_lo) << 8;
    }
    const float inv_wsum = 1.0f / (sx * sy + 1e-8f);
#pragma unroll
    for (int j = 0; j < 4; ++j) wyn[r][j] = wyt[j] * inv_wsum;
    yok[r] = (lrow[r][0] >= 0) && (lrow[r][3] <= ((SPAN - 1) << 8));
    xok[r] = (x0[r] >= 0) && (x0[r] <= Wc - 4);
  }

  const float* imgb = img + (size_t)b * Cc * HWc;
  float* outb = out + (size_t)b * Cc * HWc;

  for (int c = 0; c < Cc; ++c) {
    const float* gsrc = imgb + (size_t)c * HWc + ylo256;
    __syncthreads();  // all waves done reading previous channel
    // Stage 64 rows: 16 x global_load_lds_dwordx4 per wave (linear copy).
    // LDS dest = wave-uniform base + lane*16 (HW rule); global src per-lane.
#pragma unroll
    for (int k = 0; k < 16; ++k) {
      __builtin_amdgcn_global_load_lds(
          (glb_u32*)(gsrc + k * 1024 + t * 4),
          (lds_u32*)(smem + k * 1024 + wv * 256), 16, 0, 0);
    }
    __syncthreads();  // drains vmcnt(0): staged data visible

    const float* gimgc = imgb + (size_t)c * HWc;
    float* outc = outb + (size_t)c * HWc;
#pragma unroll
    for (int r = 0; r < TROWS; ++r) {
      float acc = 0.f;
      if (yok[r]) {
        if (xok[r]) {
          // Fast path: 4 consecutive LDS floats per tap row (-> ds_read2_b32).
#pragma unroll
          for (int i = 0; i < 4; ++i) {
            const int base = lrow[r][i] + x0[r];
            const float v0 = smem[base + 0], v1 = smem[base + 1];
            const float v2 = smem[base + 2], v3 = smem[base + 3];
            float rowv = v0 * wx[r][0];
            rowv = fmaf(v1, wx[r][1], rowv);
            rowv = fmaf(v2, wx[r][2], rowv);
            rowv = fmaf(v3, wx[r][3], rowv);
            acc = fmaf(rowv, wyn[r][i], acc);
          }
        } else {
          // x-border: clamped-index LDS gathers.
          int xi[4];
#pragma unroll
          for (int j = 0; j < 4; ++j) xi[j] = min(max(x0[r] + j, 0), Wc - 1);
#pragma unroll
          for (int i = 0; i < 4; ++i) {
            float rowv = 0.f;
#pragma unroll
            for (int j = 0; j < 4; ++j)
              rowv = fmaf(smem[lrow[r][i] + xi[j]], wx[r][j], rowv);
            acc = fmaf(rowv, wyn[r][i], acc);
          }
        }
      } else {
        // Out-of-span flow (P ~ 1.5e-4): correct global fallback.
        int xi[4];
#pragma unroll
        for (int j = 0; j < 4; ++j) xi[j] = min(max(x0[r] + j, 0), Wc - 1);
#pragma unroll
        for (int i = 0; i < 4; ++i) {
          const int rowG = lrow[r][i] + ylo256;  // = yi_clamped * 256
          float rowv = 0.f;
#pragma unroll
          for (int j = 0; j < 4; ++j)
            rowv = fmaf(gimgc[rowG + xi[j]], wx[r][j], rowv);
          acc = fmaf(rowv, wyn[r][i], acc);
        }
      }
      outc[((h0 + r) << 8) | w] = acc;  // coalesced store
    }
  }
}

extern "C" void kernel_launch(void* const* d_in, const int* in_sizes, int n_in,
                              void* d_out, int out_size, void* d_ws, size_t ws_size,
                              hipStream_t stream) {
  const float* img = (const float*)d_in[0];   // (8,64,256,256) fp32
  const float* flow = (const float*)d_in[1];  // (8,2,256,256) fp32
  float* out = (float*)d_out;                 // (8,64,256,256) fp32

  dim3 grid(Bc * (Hc / TROWS));  // 512 blocks: 8 XCD-chunks x 64 row-tiles
  dim3 block(Wc);
  hipLaunchKernelGGL(resample2d_kernel, grid, block, 0, stream, img, flow, out);
}

// Round 3
// 451.350 us; speedup vs baseline: 1.7985x; 1.2399x over previous
//
#include <hip/hip_runtime.h>

// Resample2d: B=8, C=64, H=256, W=256, ks=4, dilation=1, sigma=5.
// R1: TA/address-divergence bound -> 4 unaligned dwordx4 row-gathers/channel.
// R2: FETCH 2.07 GB (15x image) -> XCD-chunked swizzle; FETCH -> 0.3 GB (match).
// R3: still TA/L2-request bound -> stage 64-row span in LDS per channel,
//     gather from LDS (DS pipe). FETCH -> 77 MB (compulsory), dur 457->405 us.
// R4 counters: VALUBusy 9.8%, HBM 6.6%, LDS_BANK_CONFLICT 5.0e7 cyc (~20%).
//     Budget: stage 150K cyc/CU SERIALIZED (barrier drains vmcnt before
//     compute), DS ~300K, VALU ~95K, rest = barrier dead time. Structure-bound.
// R5: double-buffered channel pipeline. 512-thr blocks, 8 output rows each,
//     grid 256 (8 XCDs x 32 tiles, 1 block/CU, 8 waves), SPAN=72, LDS 2x72KB.
//     ONE __syncthreads per channel: its implicit vmcnt(0) drain retires the
//     stage issued one full channel earlier -> stage(c+1) fully overlaps
//     compute(c). Also halves per-CU L2 staging bytes (72KB vs 128KB/channel).

constexpr int Bc = 8, Cc = 64, Hc = 256, Wc = 256;
constexpr int HWc = Hc * Wc;
constexpr int SPAN = 72;          // staged rows per channel buffer
constexpr int SPANW = SPAN * Wc;  // dwords per buffer (18432)
constexpr int TROWS = 8;          // output rows per block
constexpr int NTHR = 512;

typedef __attribute__((address_space(3))) uint32_t lds_u32;
typedef const __attribute__((address_space(1))) uint32_t glb_u32;

__global__ __launch_bounds__(NTHR, 2) void resample2d_kernel(
    const float* __restrict__ img, const float* __restrict__ flow,
    float* __restrict__ out) {
  __shared__ float smem[2 * SPANW];  // 147456 B = 144 KB (<= 160 KB/CU)

  // XCD-chunked swizzle: dispatch i -> XCD (i&7); XCD k owns image b=k.
  const int b = blockIdx.x & 7;
  const int tile = blockIdx.x >> 3;  // 0..31
  const int h0 = tile << 3;          // 8 output rows per block
  const int t = threadIdx.x;         // 0..511
  const int w = t & 255;
  const int rbase = (t >> 8) << 2;   // thread handles rows h0+rbase .. +3
  const int wv = t >> 6;             // wave 0..7

  const float inv2s2 = 1.0f / 50.0f;  // 1/(2*sigma^2), sigma=5
  const int y_lo = min(max(h0 - 32, 0), Hc - SPAN);  // span [y_lo, y_lo+71]
  const int ylo256 = y_lo << 8;

  const float* flowb = flow + (size_t)b * 2 * HWc;

  // Per-output-row precompute: weights, LDS row offsets, path predicates.
  float wx[4][4], wyn[4][4];
  int lrow[4][4];  // (yi_clamped - y_lo) * 256 ; +ylo256 gives global offset
  int x0[4];
  bool yok[4], xok[4];

#pragma unroll
  for (int r = 0; r < 4; ++r) {
    const int hr = h0 + rbase + r;
    const int hw = (hr << 8) | w;
    const float fx = flowb[hw];
    const float fy = flowb[HWc + hw];
    const float xf = (float)w + fx;
    const float yf = (float)hr + fy;
    const float x0f = floorf(xf);
    const float y0f = floorf(yf);
    x0[r] = (int)x0f;
    const int y0i = (int)y0f;
    float sx = 0.f, sy = 0.f;
    float wyt[4];
#pragma unroll
    for (int j = 0; j < 4; ++j) {
      const float dx = x0f + (float)j - xf;
      wx[r][j] = __expf(-dx * dx * inv2s2);
      sx += wx[r][j];
      const float dy = y0f + (float)j - yf;
      wyt[j] = __expf(-dy * dy * inv2s2);
      sy += wyt[j];
      const int yi = min(max(y0i + j, 0), Hc - 1);
      lrow[r][j] = (yi - y_lo) << 8;
    }
    const float inv_wsum = 1.0f / (sx * sy + 1e-8f);
#pragma unroll
    for (int j = 0; j < 4; ++j) wyn[r][j] = wyt[j] * inv_wsum;
    yok[r] = (lrow[r][0] >= 0) && (lrow[r][3] <= ((SPAN - 1) << 8));
    xok[r] = (x0[r] >= 0) && (x0[r] <= Wc - 4);
  }

  const float* imgb = img + (size_t)b * Cc * HWc;
  float* outb = out + (size_t)b * Cc * HWc;

  // Prologue: stage channel 0 into buffer 0 (9 x 16B per thread = 72 KB).
  {
    const float* g = imgb + ylo256;
#pragma unroll
    for (int k = 0; k < 9; ++k) {
      __builtin_amdgcn_global_load_lds(
          (glb_u32*)(g + k * 2048 + t * 4),
          (lds_u32*)(smem + k * 2048 + wv * 256), 16, 0, 0);
    }
  }

  for (int c = 0; c < Cc; ++c) {
    // Implicit s_waitcnt vmcnt(0) lgkmcnt(0) + s_barrier:
    //  - my stage(c) slice has landed (issued one full channel ago),
    //  - everyone's compute(c-1) LDS reads are in registers,
    // so buf[c&1] is fully staged and buf[(c+1)&1] is free to overwrite.
    __syncthreads();

    if (c + 1 < Cc) {  // issue stage(c+1); overlaps with compute(c) below
      const float* g = imgb + (size_t)(c + 1) * HWc + ylo256;
      float* d = smem + ((c + 1) & 1) * SPANW;
#pragma unroll
      for (int k = 0; k < 9; ++k) {
        __builtin_amdgcn_global_load_lds(
            (glb_u32*)(g + k * 2048 + t * 4),
            (lds_u32*)(d + k * 2048 + wv * 256), 16, 0, 0);
      }
    }

    const float* scur = smem + (c & 1) * SPANW;
    const float* gimgc = imgb + (size_t)c * HWc;  // out-of-span fallback
    float* outc = outb + (size_t)c * HWc;

#pragma unroll
    for (int r = 0; r < 4; ++r) {
      float acc = 0.f;
      if (yok[r]) {
        if (xok[r]) {
          // Fast path: 4 consecutive LDS floats per tap row (ds_read2_b32 x2).
#pragma unroll
          for (int i = 0; i < 4; ++i) {
            const int base = lrow[r][i] + x0[r];
            const float v0 = scur[base + 0], v1 = scur[base + 1];
            const float v2 = scur[base + 2], v3 = scur[base + 3];
            float rowv = v0 * wx[r][0];
            rowv = fmaf(v1, wx[r][1], rowv);
            rowv = fmaf(v2, wx[r][2], rowv);
            rowv = fmaf(v3, wx[r][3], rowv);
            acc = fmaf(rowv, wyn[r][i], acc);
          }
        } else {
          // x-border: clamped-index LDS gathers.
          int xi[4];
#pragma unroll
          for (int j = 0; j < 4; ++j) xi[j] = min(max(x0[r] + j, 0), Wc - 1);
#pragma unroll
          for (int i = 0; i < 4; ++i) {
            float rowv = 0.f;
#pragma unroll
            for (int j = 0; j < 4; ++j)
              rowv = fmaf(scur[lrow[r][i] + xi[j]], wx[r][j], rowv);
            acc = fmaf(rowv, wyn[r][i], acc);
          }
        }
      } else {
        // Out-of-span flow (P ~ 6e-5 per pixel): correct global fallback.
        int xi[4];
#pragma unroll
        for (int j = 0; j < 4; ++j) xi[j] = min(max(x0[r] + j, 0), Wc - 1);
#pragma unroll
        for (int i = 0; i < 4; ++i) {
          const int rowG = lrow[r][i] + ylo256;  // = yi_clamped * 256
          float rowv = 0.f;
#pragma unroll
          for (int j = 0; j < 4; ++j)
            rowv = fmaf(gimgc[rowG + xi[j]], wx[r][j], rowv);
          acc = fmaf(rowv, wyn[r][i], acc);
        }
      }
      outc[((h0 + rbase + r) << 8) | w] = acc;  // coalesced store
    }
  }
}

extern "C" void kernel_launch(void* const* d_in, const int* in_sizes, int n_in,
                              void* d_out, int out_size, void* d_ws, size_t ws_size,
                              hipStream_t stream) {
  const float* img = (const float*)d_in[0];   // (8,64,256,256) fp32
  const float* flow = (const float*)d_in[1];  // (8,2,256,256) fp32
  float* out = (float*)d_out;                 // (8,64,256,256) fp32

  dim3 grid(Bc * (Hc / TROWS));  // 256 blocks: 8 XCD-chunks x 32 row-tiles
  dim3 block(NTHR);
  hipLaunchKernelGGL(resample2d_kernel, grid, block, 0, stream, img, flow, out);
}

// Round 4
// 408.997 us; speedup vs baseline: 1.9847x; 1.1036x over previous
//
#include <hip/hip_runtime.h>

// Resample2d: B=8, C=64, H=256, W=256, ks=4, dilation=1, sigma=5.
// R1: TA/address-divergence bound -> 4 unaligned dwordx4 row-gathers/channel.
// R2: FETCH 2.07 GB (15x image) -> XCD-chunked swizzle; FETCH -> 0.3 GB (match).
// R3: still TA/L2-request bound -> stage row-span in LDS, gather from LDS.
//     FETCH -> 77 MB (compulsory), dur 457->405 us.
// R4: serialized stage->compute chain -> R5 double-buffered channel pipeline
//     (one __syncthreads/channel retires stage issued a full channel earlier).
//     dur 405->296 us profiled.
// R5 counters: DS pipe ~37% busy (min 1K + 3K conflict cyc/ch/CU), VALU 17%,
//     stage overlapped, Occupancy 20% (144 KB LDS -> 1 block/CU = 8 waves).
//     No pipe saturated -> LATENCY-BOUND at 8 waves.
// R6: 1024-thread blocks (16 waves = VGPR-128 occupancy cap), 2 output rows
//     per thread, SPAN 72->64 (2x64 KB = 128 KB dbuf, stage = 4x16B/thread).
//     Grid stays 256 = 1 block/CU. Same pipeline, twice the latency hiding.

constexpr int Bc = 8, Cc = 64, Hc = 256, Wc = 256;
constexpr int HWc = Hc * Wc;
constexpr int SPAN = 64;          // staged rows per channel buffer
constexpr int SPANW = SPAN * Wc;  // dwords per buffer (16384)
constexpr int TROWS = 8;          // output rows per block
constexpr int NTHR = 1024;        // 16 waves

typedef __attribute__((address_space(3))) uint32_t lds_u32;
typedef const __attribute__((address_space(1))) uint32_t glb_u32;

__global__ __launch_bounds__(NTHR, 4) void resample2d_kernel(
    const float* __restrict__ img, const float* __restrict__ flow,
    float* __restrict__ out) {
  __shared__ float smem[2 * SPANW];  // 131072 B = 128 KB (<= 160 KB/CU)

  // XCD-chunked swizzle: dispatch i -> XCD (i&7); XCD k owns image b=k.
  const int b = blockIdx.x & 7;
  const int tile = blockIdx.x >> 3;  // 0..31
  const int h0 = tile << 3;          // 8 output rows per block
  const int t = threadIdx.x;         // 0..1023
  const int w = t & 255;
  const int rbase = (t >> 8) << 1;   // thread handles rows h0+rbase, +1
  const int wv = t >> 6;             // wave 0..15

  const float inv2s2 = 1.0f / 50.0f;  // 1/(2*sigma^2), sigma=5
  const int y_lo = min(max(h0 - 28, 0), Hc - SPAN);  // span [y_lo, y_lo+63]
  const int ylo256 = y_lo << 8;

  const float* flowb = flow + (size_t)b * 2 * HWc;

  // Per-output-row precompute: weights, LDS row offsets, path predicates.
  float wx[2][4], wyn[2][4];
  int lrow[2][4];  // (yi_clamped - y_lo) * 256 ; +ylo256 gives global offset
  int x0[2];
  bool yok[2], xok[2];

#pragma unroll
  for (int r = 0; r < 2; ++r) {
    const int hr = h0 + rbase + r;
    const int hw = (hr << 8) | w;
    const float fx = flowb[hw];
    const float fy = flowb[HWc + hw];
    const float xf = (float)w + fx;
    const float yf = (float)hr + fy;
    const float x0f = floorf(xf);
    const float y0f = floorf(yf);
    x0[r] = (int)x0f;
    const int y0i = (int)y0f;
    float sx = 0.f, sy = 0.f;
    float wyt[4];
#pragma unroll
    for (int j = 0; j < 4; ++j) {
      const float dx = x0f + (float)j - xf;
      wx[r][j] = __expf(-dx * dx * inv2s2);
      sx += wx[r][j];
      const float dy = y0f + (float)j - yf;
      wyt[j] = __expf(-dy * dy * inv2s2);
      sy += wyt[j];
      const int yi = min(max(y0i + j, 0), Hc - 1);
      lrow[r][j] = (yi - y_lo) << 8;
    }
    const float inv_wsum = 1.0f / (sx * sy + 1e-8f);
#pragma unroll
    for (int j = 0; j < 4; ++j) wyn[r][j] = wyt[j] * inv_wsum;
    yok[r] = (lrow[r][0] >= 0) && (lrow[r][3] <= ((SPAN - 1) << 8));
    xok[r] = (x0[r] >= 0) && (x0[r] <= Wc - 4);
  }

  const float* imgb = img + (size_t)b * Cc * HWc;
  float* outb = out + (size_t)b * Cc * HWc;

  // Prologue: stage channel 0 into buffer 0 (4 x 16B per thread = 64 KB).
  {
    const float* g = imgb + ylo256;
#pragma unroll
    for (int k = 0; k < 4; ++k) {
      __builtin_amdgcn_global_load_lds(
          (glb_u32*)(g + k * 4096 + t * 4),
          (lds_u32*)(smem + k * 4096 + wv * 256), 16, 0, 0);
    }
  }

  for (int c = 0; c < Cc; ++c) {
    // Implicit s_waitcnt vmcnt(0) lgkmcnt(0) + s_barrier:
    //  - my stage(c) slice has landed (issued one full channel ago),
    //  - everyone's compute(c-1) LDS reads are in registers,
    // so buf[c&1] is fully staged and buf[(c+1)&1] is free to overwrite.
    __syncthreads();

    if (c + 1 < Cc) {  // issue stage(c+1); overlaps with compute(c) below
      const float* g = imgb + (size_t)(c + 1) * HWc + ylo256;
      float* d = smem + ((c + 1) & 1) * SPANW;
#pragma unroll
      for (int k = 0; k < 4; ++k) {
        __builtin_amdgcn_global_load_lds(
            (glb_u32*)(g + k * 4096 + t * 4),
            (lds_u32*)(d + k * 4096 + wv * 256), 16, 0, 0);
      }
    }

    const float* scur = smem + (c & 1) * SPANW;
    const float* gimgc = imgb + (size_t)c * HWc;  // out-of-span fallback
    float* outc = outb + (size_t)c * HWc;

#pragma unroll
    for (int r = 0; r < 2; ++r) {
      float acc = 0.f;
      if (yok[r]) {
        if (xok[r]) {
          // Fast path: 4 consecutive LDS floats per tap row (ds_read2_b32 x2).
#pragma unroll
          for (int i = 0; i < 4; ++i) {
            const int base = lrow[r][i] + x0[r];
            const float v0 = scur[base + 0], v1 = scur[base + 1];
            const float v2 = scur[base + 2], v3 = scur[base + 3];
            float rowv = v0 * wx[r][0];
            rowv = fmaf(v1, wx[r][1], rowv);
            rowv = fmaf(v2, wx[r][2], rowv);
            rowv = fmaf(v3, wx[r][3], rowv);
            acc = fmaf(rowv, wyn[r][i], acc);
          }
        } else {
          // x-border: clamped-index LDS gathers.
          int xi[4];
#pragma unroll
          for (int j = 0; j < 4; ++j) xi[j] = min(max(x0[r] + j, 0), Wc - 1);
#pragma unroll
          for (int i = 0; i < 4; ++i) {
            float rowv = 0.f;
#pragma unroll
            for (int j = 0; j < 4; ++j)
              rowv = fmaf(scur[lrow[r][i] + xi[j]], wx[r][j], rowv);
            acc = fmaf(rowv, wyn[r][i], acc);
          }
        }
      } else {
        // Out-of-span flow (P ~ 1.5e-3 per output): correct global fallback.
        int xi[4];
#pragma unroll
        for (int j = 0; j < 4; ++j) xi[j] = min(max(x0[r] + j, 0), Wc - 1);
#pragma unroll
        for (int i = 0; i < 4; ++i) {
          const int rowG = lrow[r][i] + ylo256;  // = yi_clamped * 256
          float rowv = 0.f;
#pragma unroll
          for (int j = 0; j < 4; ++j)
            rowv = fmaf(gimgc[rowG + xi[j]], wx[r][j], rowv);
          acc = fmaf(rowv, wyn[r][i], acc);
        }
      }
      outc[((h0 + rbase + r) << 8) | w] = acc;  // coalesced store
    }
  }
}

extern "C" void kernel_launch(void* const* d_in, const int* in_sizes, int n_in,
                              void* d_out, int out_size, void* d_ws, size_t ws_size,
                              hipStream_t stream) {
  const float* img = (const float*)d_in[0];   // (8,64,256,256) fp32
  const float* flow = (const float*)d_in[1];  // (8,2,256,256) fp32
  float* out = (float*)d_out;                 // (8,64,256,256) fp32

  dim3 grid(Bc * (Hc / TROWS));  // 256 blocks: 8 XCD-chunks x 32 row-tiles
  dim3 block(NTHR);
  hipLaunchKernelGGL(resample2d_kernel, grid, block, 0, stream, img, flow, out);
}